// Round 9
// baseline (411.061 us; speedup 1.0000x reference)
//
#include <hip/hip_runtime.h>

// B=4, T=2048, D=1024, H=16, hd=64. Inputs/output fp32; internal bf16 MFMA.
// R9: attn v3 — S^T MFMA layout (b64 packed P stores, b128 readback), l via
// ones-MFMA (no per-elem adds, no epilogue shuffles), mask only on the 2
// diagonal tiles, 1024 blocks (4/CU, heavy-first), xor-swizzled Vt (aligned
// b128 V-frag reads). GEMMs: global_load_lds width-16 staging (m97 ladder).

typedef __bf16 bf16;
typedef __attribute__((ext_vector_type(8))) __bf16 bf16x8;
typedef __attribute__((ext_vector_type(4))) __bf16 bf16x4;
typedef __attribute__((ext_vector_type(4))) float f4;

#define BK 32

__device__ __forceinline__ void stage16(const bf16* g, bf16* l) {
    __builtin_amdgcn_global_load_lds((const __attribute__((address_space(1))) void*)g,
                                     (__attribute__((address_space(3))) void*)l,
                                     16, 0, 0);
}

// ---------------- cast fp32 -> bf16, vectorized ---------------------------
__global__ __launch_bounds__(256)
void cast_f32_bf16(const float* __restrict__ src, bf16* __restrict__ dst, int n4)
{
    int i = blockIdx.x * 256 + threadIdx.x;
    if (i < n4) {
        float4 v = ((const float4*)src)[i];
        bf16x4 o = { (bf16)v.x, (bf16)v.y, (bf16)v.z, (bf16)v.w };
        *(bf16x4*)&dst[i * 4] = o;
    }
}

// ---------------- transpose + cast: fp32 src [R][C] -> bf16 dst [C][R] ----
__global__ __launch_bounds__(256)
void transpose_f32_bf16(const float* __restrict__ src, bf16* __restrict__ dst,
                        int R, int C)
{
    __shared__ bf16 tile[64][65];
    int c0 = blockIdx.x * 64, r0 = blockIdx.y * 64;
    int tid = threadIdx.x;
    for (int i = tid; i < 64 * 64; i += 256) {
        int r = i >> 6, c = i & 63;
        tile[r][c] = (bf16)src[(long)(r0 + r) * C + c0 + c];
    }
    __syncthreads();
    for (int i = tid; i < 64 * 64; i += 256) {
        int r = i >> 6, c = i & 63;
        dst[(long)(c0 + r) * R + r0 + c] = tile[c][r];
    }
}

// ---------------- GEMM: C[M,N] = A[M,K] x Bt[N,K]^T, bf16 in, OutT out ----
// 128x128 tile, BK=32, global_load_lds width-16 staging (m97 pattern).
template <typename OutT>
__global__ __launch_bounds__(256)
void gemm_bt(const bf16* __restrict__ A, const bf16* __restrict__ Bt,
             OutT* __restrict__ C, int M, int N, int K, int lda, int ldc)
{
    __shared__ bf16 As[128 * BK];
    __shared__ bf16 Bs[128 * BK];
    int tid = threadIdx.x;
    int lane = tid & 63;
    int wid = tid >> 6;
    int wy = wid >> 1, wx = wid & 1;
    int m0 = blockIdx.y * 128, n0 = blockIdx.x * 128;

    f4 acc[4][4];
    #pragma unroll
    for (int mi = 0; mi < 4; ++mi)
        #pragma unroll
        for (int ni = 0; ni < 4; ++ni)
            acc[mi][ni] = (f4){0.f, 0.f, 0.f, 0.f};

    int srow = lane >> 2;          // 0..15 within a 16-row chunk
    int scol = (lane & 3) * 8;     // 8 bf16 = 16B per lane
    for (int kt = 0; kt < K; kt += BK) {
        #pragma unroll
        for (int i = 0; i < 2; ++i) {
            int chunk = wid * 2 + i;           // 0..7, 16 rows each
            int row = chunk * 16 + srow;
            // LDS dest = wave-uniform base (chunk*1024B) + lane*16B
            stage16(A  + (long)(m0 + row) * lda + kt + scol, As + chunk * 512 + lane * 8);
            stage16(Bt + (long)(n0 + row) * K   + kt + scol, Bs + chunk * 512 + lane * 8);
        }
        __syncthreads();   // drains vmcnt(0) -> staging visible
        bf16x8 af[4], bfr[4];
        #pragma unroll
        for (int mi = 0; mi < 4; ++mi)
            af[mi] = *(const bf16x8*)&As[(wy * 64 + mi * 16 + (lane & 15)) * BK + (lane >> 4) * 8];
        #pragma unroll
        for (int ni = 0; ni < 4; ++ni)
            bfr[ni] = *(const bf16x8*)&Bs[(wx * 64 + ni * 16 + (lane & 15)) * BK + (lane >> 4) * 8];
        #pragma unroll
        for (int mi = 0; mi < 4; ++mi)
            #pragma unroll
            for (int ni = 0; ni < 4; ++ni)
                acc[mi][ni] = __builtin_amdgcn_mfma_f32_16x16x32_bf16(af[mi], bfr[ni], acc[mi][ni], 0, 0, 0);
        __syncthreads();
    }
    #pragma unroll
    for (int mi = 0; mi < 4; ++mi) {
        int rbase = m0 + wy * 64 + mi * 16 + (lane >> 4) * 4;
        #pragma unroll
        for (int ni = 0; ni < 4; ++ni) {
            int col = n0 + wx * 64 + ni * 16 + (lane & 15);
            #pragma unroll
            for (int r = 0; r < 4; ++r)
                C[(long)(rbase + r) * ldc + col] = (OutT)acc[mi][ni][r];
        }
    }
}

// ---------------- MFMA flash attention, v3 --------------------------------
// Block = (b, h, 128-row q-tile), 4 waves x 32 q. Per 64-key tile:
// S^T = K Q^T (A=K frags from LDS, B=Q frags held in regs); fixed-max
// softmax p=exp2(s*c-16) with packed bf16x4 stores into row-major P[q][k];
// O += P V and l += P*1 (const ones B-frag) via MFMA; mask only on the two
// diagonal tiles. Vt xor-swizzled (stride 64) for aligned b128 reads.
#define QS 72
#define C_SL 0.18033688011112042f   // 0.125 * log2(e)

__device__ __forceinline__ int vsw(int d, int k) {
    return d * 64 + ((((k >> 3) ^ (d & 7) ^ ((d >> 3) & 7)) & 7) << 3) + (k & 7);
}

__global__ __launch_bounds__(256, 4)
void attn_mfma(bf16* __restrict__ qkv)
{
    __shared__ bf16 Ks[64 * QS];        //  9.2 KB
    __shared__ bf16 Vt[64 * 64];        //  8.0 KB (swizzled)
    __shared__ bf16 Ps[4 * 32 * QS];    // 18.4 KB
    const int T = 2048, D3 = 3072;
    int tid = threadIdx.x;
    int lane = tid & 63, wid = tid >> 6;
    int quad = lane >> 4, col = lane & 15;
    int bh = blockIdx.x & 63;
    int qt = 15 - (blockIdx.x >> 6);     // heavy tiles dispatched first
    int b = bh >> 4, h = bh & 15;
    long base = (long)b * T * D3 + h * 64;
    int q0 = qt * 128;
    int nk = 2 * qt + 2;
    int srow = tid >> 2, dseg = (tid & 3) * 16;   // 64x64 staging map
    bf16* Pw = &Ps[wid * 32 * QS];

    // Q B-frags (held in regs): lane holds Q[q=nt*16+col][d=quad*8+j+32*ch]
    bf16x8 aq[2][2];
    #pragma unroll
    for (int nt = 0; nt < 2; ++nt) {
        const bf16* g = &qkv[base + (long)(q0 + wid * 32 + nt * 16 + col) * D3 + quad * 8];
        aq[nt][0] = *(const bf16x8*)g;
        aq[nt][1] = *(const bf16x8*)(g + 32);
    }
    bf16 one1 = (bf16)1.0f;
    bf16x8 bones = {one1, one1, one1, one1, one1, one1, one1, one1};

    f4 of[2][4], lac[2];
    #pragma unroll
    for (int mg = 0; mg < 2; ++mg) {
        lac[mg] = (f4){0.f, 0.f, 0.f, 0.f};
        #pragma unroll
        for (int n = 0; n < 4; ++n) of[mg][n] = (f4){0.f, 0.f, 0.f, 0.f};
    }

    // prefetch k-tile 0
    const bf16* g0 = &qkv[base + (long)srow * D3 + 1024 + dseg];
    bf16x8 kr0 = *(const bf16x8*)g0;
    bf16x8 kr1 = *(const bf16x8*)(g0 + 8);
    bf16x8 vr0 = *(const bf16x8*)(g0 + 1024);
    bf16x8 vr1 = *(const bf16x8*)(g0 + 1032);

    for (int kt = 0; kt < nk; ++kt) {
        __syncthreads();                 // prior iter's LDS reads done
        *(bf16x8*)&Ks[srow * QS + dseg]     = kr0;
        *(bf16x8*)&Ks[srow * QS + dseg + 8] = kr1;
        #pragma unroll
        for (int j = 0; j < 8; ++j) {
            Vt[vsw(dseg + j, srow)]     = vr0[j];
            Vt[vsw(dseg + 8 + j, srow)] = vr1[j];
        }
        if (kt + 1 < nk) {               // latency hidden behind compute
            const bf16* gn = &qkv[base + (long)((kt + 1) * 64 + srow) * D3 + 1024 + dseg];
            kr0 = *(const bf16x8*)gn;
            kr1 = *(const bf16x8*)(gn + 8);
            vr0 = *(const bf16x8*)(gn + 1024);
            vr1 = *(const bf16x8*)(gn + 1032);
        }
        __syncthreads();
        // S^T = K Q^T : element (k = mt*16+quad*4+r, q = nt*16+col)
        f4 st[4][2];
        #pragma unroll
        for (int mt = 0; mt < 4; ++mt) {
            bf16x8 ak0 = *(const bf16x8*)&Ks[(mt * 16 + col) * QS + quad * 8];
            bf16x8 ak1 = *(const bf16x8*)&Ks[(mt * 16 + col) * QS + 32 + quad * 8];
            #pragma unroll
            for (int nt = 0; nt < 2; ++nt) {
                f4 z = (f4){0.f, 0.f, 0.f, 0.f};
                z = __builtin_amdgcn_mfma_f32_16x16x32_bf16(ak0, aq[nt][0], z, 0, 0, 0);
                st[mt][nt] = __builtin_amdgcn_mfma_f32_16x16x32_bf16(ak1, aq[nt][1], z, 0, 0, 0);
            }
        }
        // softmax + packed P store (mask only on the 2 diagonal tiles)
        if (kt < nk - 2) {
            #pragma unroll
            for (int mt = 0; mt < 4; ++mt)
                #pragma unroll
                for (int nt = 0; nt < 2; ++nt) {
                    bf16x4 pk;
                    #pragma unroll
                    for (int r = 0; r < 4; ++r)
                        pk[r] = (bf16)exp2f(fmaf(st[mt][nt][r], C_SL, -16.f));
                    *(bf16x4*)&Pw[(nt * 16 + col) * QS + mt * 16 + quad * 4] = pk;
                }
        } else {
            int k0 = kt * 64;
            #pragma unroll
            for (int mt = 0; mt < 4; ++mt)
                #pragma unroll
                for (int nt = 0; nt < 2; ++nt) {
                    int qg = q0 + wid * 32 + nt * 16 + col;
                    bf16x4 pk;
                    #pragma unroll
                    for (int r = 0; r < 4; ++r) {
                        float arg = fmaf(st[mt][nt][r], C_SL, -16.f);
                        if ((k0 + mt * 16 + quad * 4 + r) > qg) arg = -1e30f;
                        pk[r] = (bf16)exp2f(arg);
                    }
                    *(bf16x4*)&Pw[(nt * 16 + col) * QS + mt * 16 + quad * 4] = pk;
                }
        }
        // P readback (wave-private, no barrier) + O += P V, l += P 1
        #pragma unroll
        for (int mg = 0; mg < 2; ++mg) {
            bf16x8 ap0 = *(const bf16x8*)&Pw[(mg * 16 + col) * QS + quad * 8];
            bf16x8 ap1 = *(const bf16x8*)&Pw[(mg * 16 + col) * QS + 32 + quad * 8];
            #pragma unroll
            for (int nd = 0; nd < 4; ++nd) {
                bf16x8 bv0 = *(const bf16x8*)&Vt[vsw(nd * 16 + col, quad * 8)];
                bf16x8 bv1 = *(const bf16x8*)&Vt[vsw(nd * 16 + col, 32 + quad * 8)];
                of[mg][nd] = __builtin_amdgcn_mfma_f32_16x16x32_bf16(ap0, bv0, of[mg][nd], 0, 0, 0);
                of[mg][nd] = __builtin_amdgcn_mfma_f32_16x16x32_bf16(ap1, bv1, of[mg][nd], 0, 0, 0);
            }
            lac[mg] = __builtin_amdgcn_mfma_f32_16x16x32_bf16(ap0, bones, lac[mg], 0, 0, 0);
            lac[mg] = __builtin_amdgcn_mfma_f32_16x16x32_bf16(ap1, bones, lac[mg], 0, 0, 0);
        }
    }
    // epilogue: y into this block's dead Q region; l is in O's C-layout
    #pragma unroll
    for (int mg = 0; mg < 2; ++mg)
        #pragma unroll
        for (int r = 0; r < 4; ++r) {
            float inv = 1.f / lac[mg][r];
            long yoff = base + (long)(q0 + wid * 32 + mg * 16 + quad * 4 + r) * D3;
            #pragma unroll
            for (int nd = 0; nd < 4; ++nd)
                qkv[yoff + nd * 16 + col] = (bf16)(of[mg][nd][r] * inv);
        }
}

// --------------------------------------------------------------------------
extern "C" void kernel_launch(void* const* d_in, const int* in_sizes, int n_in,
                              void* d_out, int out_size, void* d_ws, size_t ws_size,
                              hipStream_t stream) {
    const float* x      = (const float*)d_in[0];  // [8192,1024] fp32
    const float* W_attn = (const float*)d_in[1];  // [1024,3072] fp32
    const float* W_proj = (const float*)d_in[2];  // [1024,1024] fp32
    float* out = (float*)d_out;                   // [8192,1024] fp32

    // ws layout (58.7 MB): qkv | WtA | WtP
    bf16* qkv = (bf16*)d_ws;                         // [8192,3072]  50.3 MB
    bf16* WtA = qkv + (size_t)8192 * 3072;           // [3072,1024]   6.3 MB
    bf16* WtP = WtA + (size_t)3072 * 1024;           // [1024,1024]   2.1 MB
    bf16* xb = (bf16*)d_out;   // bf16 x staged in d_out; dead before gemm2

    cast_f32_bf16<<<8192, 256, 0, stream>>>(x, xb, 8192 * 1024 / 4);
    transpose_f32_bf16<<<dim3(48, 16), 256, 0, stream>>>(W_attn, WtA, 1024, 3072);
    transpose_f32_bf16<<<dim3(16, 16), 256, 0, stream>>>(W_proj, WtP, 1024, 1024);
    // qkv = xb @ W_attn  (bf16 out)
    gemm_bt<bf16><<<dim3(24, 64), 256, 0, stream>>>(xb, WtA, qkv, 8192, 3072,
                                                    1024, 1024, 3072);
    // MFMA flash attention; y written into qkv's Q columns
    attn_mfma<<<1024, 256, 0, stream>>>(qkv);
    // out = y @ W_proj  (y = qkv cols 0..1023, row stride 3072; fp32 out)
    gemm_bt<float><<<dim3(8, 64), 256, 0, stream>>>(qkv, WtP, out, 8192, 1024,
                                                    1024, 3072, 1024);
}

// Round 10
// 281.550 us; speedup vs baseline: 1.4600x; 1.4600x over previous
//
#include <hip/hip_runtime.h>

// B=4, T=2048, D=1024, H=16, hd=64. Inputs/output fp32; internal bf16 MFMA.
// R10: revert R9's __launch_bounds__(256,4) — it forced VGPRs to 64 and
// spilled the hot loop to scratch (WRITE_SIZE 157 MB). Keep R9 structure
// (S^T MFMA, packed P stores, ones-MFMA l, diag-only mask, swizzled Vt),
// but fuse softmax per 16-row k-chunk to cut peak live registers.

typedef __bf16 bf16;
typedef __attribute__((ext_vector_type(8))) __bf16 bf16x8;
typedef __attribute__((ext_vector_type(4))) __bf16 bf16x4;
typedef __attribute__((ext_vector_type(4))) float f4;

#define BK 32

__device__ __forceinline__ void stage16(const bf16* g, bf16* l) {
    __builtin_amdgcn_global_load_lds((const __attribute__((address_space(1))) void*)g,
                                     (__attribute__((address_space(3))) void*)l,
                                     16, 0, 0);
}

// ---------------- cast fp32 -> bf16, vectorized ---------------------------
__global__ __launch_bounds__(256)
void cast_f32_bf16(const float* __restrict__ src, bf16* __restrict__ dst, int n4)
{
    int i = blockIdx.x * 256 + threadIdx.x;
    if (i < n4) {
        float4 v = ((const float4*)src)[i];
        bf16x4 o = { (bf16)v.x, (bf16)v.y, (bf16)v.z, (bf16)v.w };
        *(bf16x4*)&dst[i * 4] = o;
    }
}

// ---------------- transpose + cast: fp32 src [R][C] -> bf16 dst [C][R] ----
__global__ __launch_bounds__(256)
void transpose_f32_bf16(const float* __restrict__ src, bf16* __restrict__ dst,
                        int R, int C)
{
    __shared__ bf16 tile[64][65];
    int c0 = blockIdx.x * 64, r0 = blockIdx.y * 64;
    int tid = threadIdx.x;
    for (int i = tid; i < 64 * 64; i += 256) {
        int r = i >> 6, c = i & 63;
        tile[r][c] = (bf16)src[(long)(r0 + r) * C + c0 + c];
    }
    __syncthreads();
    for (int i = tid; i < 64 * 64; i += 256) {
        int r = i >> 6, c = i & 63;
        dst[(long)(c0 + r) * R + r0 + c] = tile[c][r];
    }
}

// ---------------- GEMM: C[M,N] = A[M,K] x Bt[N,K]^T, bf16 in, OutT out ----
// 128x128 tile, BK=32, global_load_lds width-16 staging (m97 pattern).
template <typename OutT>
__global__ __launch_bounds__(256)
void gemm_bt(const bf16* __restrict__ A, const bf16* __restrict__ Bt,
             OutT* __restrict__ C, int M, int N, int K, int lda, int ldc)
{
    __shared__ bf16 As[128 * BK];
    __shared__ bf16 Bs[128 * BK];
    int tid = threadIdx.x;
    int lane = tid & 63;
    int wid = tid >> 6;
    int wy = wid >> 1, wx = wid & 1;
    int m0 = blockIdx.y * 128, n0 = blockIdx.x * 128;

    f4 acc[4][4];
    #pragma unroll
    for (int mi = 0; mi < 4; ++mi)
        #pragma unroll
        for (int ni = 0; ni < 4; ++ni)
            acc[mi][ni] = (f4){0.f, 0.f, 0.f, 0.f};

    int srow = lane >> 2;
    int scol = (lane & 3) * 8;
    for (int kt = 0; kt < K; kt += BK) {
        #pragma unroll
        for (int i = 0; i < 2; ++i) {
            int chunk = wid * 2 + i;
            int row = chunk * 16 + srow;
            stage16(A  + (long)(m0 + row) * lda + kt + scol, As + chunk * 512 + lane * 8);
            stage16(Bt + (long)(n0 + row) * K   + kt + scol, Bs + chunk * 512 + lane * 8);
        }
        __syncthreads();
        bf16x8 af[4], bfr[4];
        #pragma unroll
        for (int mi = 0; mi < 4; ++mi)
            af[mi] = *(const bf16x8*)&As[(wy * 64 + mi * 16 + (lane & 15)) * BK + (lane >> 4) * 8];
        #pragma unroll
        for (int ni = 0; ni < 4; ++ni)
            bfr[ni] = *(const bf16x8*)&Bs[(wx * 64 + ni * 16 + (lane & 15)) * BK + (lane >> 4) * 8];
        #pragma unroll
        for (int mi = 0; mi < 4; ++mi)
            #pragma unroll
            for (int ni = 0; ni < 4; ++ni)
                acc[mi][ni] = __builtin_amdgcn_mfma_f32_16x16x32_bf16(af[mi], bfr[ni], acc[mi][ni], 0, 0, 0);
        __syncthreads();
    }
    #pragma unroll
    for (int mi = 0; mi < 4; ++mi) {
        int rbase = m0 + wy * 64 + mi * 16 + (lane >> 4) * 4;
        #pragma unroll
        for (int ni = 0; ni < 4; ++ni) {
            int col = n0 + wx * 64 + ni * 16 + (lane & 15);
            #pragma unroll
            for (int r = 0; r < 4; ++r)
                C[(long)(rbase + r) * ldc + col] = (OutT)acc[mi][ni][r];
        }
    }
}

// ---------------- MFMA flash attention, v4 --------------------------------
// Block = (b, h, 128-row q-tile), 4 waves x 32 q. Per 64-key tile:
// S^T = K Q^T per 16-row k-chunk (fused MFMA -> softmax -> packed bf16x4
// store, bounds live regs); O += P V and l += P*1 via MFMA; mask only on
// the 2 diagonal tiles; Vt xor-swizzled for aligned b128 reads.
#define QS 72
#define C_SL 0.18033688011112042f   // 0.125 * log2(e)

__device__ __forceinline__ int vsw(int d, int k) {
    return d * 64 + ((((k >> 3) ^ (d & 7) ^ ((d >> 3) & 7)) & 7) << 3) + (k & 7);
}

__global__ __launch_bounds__(256)
void attn_mfma(bf16* __restrict__ qkv)
{
    __shared__ bf16 Ks[64 * QS];        //  9.2 KB
    __shared__ bf16 Vt[64 * 64];        //  8.0 KB (swizzled)
    __shared__ bf16 Ps[4 * 32 * QS];    // 18.4 KB
    const int T = 2048, D3 = 3072;
    int tid = threadIdx.x;
    int lane = tid & 63, wid = tid >> 6;
    int quad = lane >> 4, col = lane & 15;
    int bh = blockIdx.x & 63;
    int qt = 15 - (blockIdx.x >> 6);     // heavy tiles dispatched first
    int b = bh >> 4, h = bh & 15;
    long base = (long)b * T * D3 + h * 64;
    int q0 = qt * 128;
    int nk = 2 * qt + 2;
    int srow = tid >> 2, dseg = (tid & 3) * 16;   // 64x64 staging map
    bf16* Pw = &Ps[wid * 32 * QS];

    // Q B-frags (held in regs): lane holds Q[q=nt*16+col][d=quad*8+j+32*ch]
    bf16x8 aq[2][2];
    #pragma unroll
    for (int nt = 0; nt < 2; ++nt) {
        const bf16* g = &qkv[base + (long)(q0 + wid * 32 + nt * 16 + col) * D3 + quad * 8];
        aq[nt][0] = *(const bf16x8*)g;
        aq[nt][1] = *(const bf16x8*)(g + 32);
    }
    bf16 one1 = (bf16)1.0f;
    bf16x8 bones = {one1, one1, one1, one1, one1, one1, one1, one1};

    f4 of[2][4], lac[2];
    #pragma unroll
    for (int mg = 0; mg < 2; ++mg) {
        lac[mg] = (f4){0.f, 0.f, 0.f, 0.f};
        #pragma unroll
        for (int n = 0; n < 4; ++n) of[mg][n] = (f4){0.f, 0.f, 0.f, 0.f};
    }

    // prefetch k-tile 0
    const bf16* g0 = &qkv[base + (long)srow * D3 + 1024 + dseg];
    bf16x8 kr0 = *(const bf16x8*)g0;
    bf16x8 kr1 = *(const bf16x8*)(g0 + 8);
    bf16x8 vr0 = *(const bf16x8*)(g0 + 1024);
    bf16x8 vr1 = *(const bf16x8*)(g0 + 1032);

    for (int kt = 0; kt < nk; ++kt) {
        __syncthreads();                 // prior iter's LDS reads done
        *(bf16x8*)&Ks[srow * QS + dseg]     = kr0;
        *(bf16x8*)&Ks[srow * QS + dseg + 8] = kr1;
        #pragma unroll
        for (int j = 0; j < 8; ++j) {
            Vt[vsw(dseg + j, srow)]     = vr0[j];
            Vt[vsw(dseg + 8 + j, srow)] = vr1[j];
        }
        if (kt + 1 < nk) {               // latency hidden behind compute
            const bf16* gn = &qkv[base + (long)((kt + 1) * 64 + srow) * D3 + 1024 + dseg];
            kr0 = *(const bf16x8*)gn;
            kr1 = *(const bf16x8*)(gn + 8);
            vr0 = *(const bf16x8*)(gn + 1024);
            vr1 = *(const bf16x8*)(gn + 1032);
        }
        __syncthreads();
        // S^T = K Q^T, fused per 16-row k-chunk (bounds live registers)
        bool diag = (kt >= nk - 2);
        int k0 = kt * 64;
        #pragma unroll
        for (int mt = 0; mt < 4; ++mt) {
            bf16x8 ak0 = *(const bf16x8*)&Ks[(mt * 16 + col) * QS + quad * 8];
            bf16x8 ak1 = *(const bf16x8*)&Ks[(mt * 16 + col) * QS + 32 + quad * 8];
            #pragma unroll
            for (int nt = 0; nt < 2; ++nt) {
                f4 z = (f4){0.f, 0.f, 0.f, 0.f};
                z = __builtin_amdgcn_mfma_f32_16x16x32_bf16(ak0, aq[nt][0], z, 0, 0, 0);
                f4 st = __builtin_amdgcn_mfma_f32_16x16x32_bf16(ak1, aq[nt][1], z, 0, 0, 0);
                bf16x4 pk;
                if (diag) {
                    int qg = q0 + wid * 32 + nt * 16 + col;
                    #pragma unroll
                    for (int r = 0; r < 4; ++r) {
                        float arg = fmaf(st[r], C_SL, -16.f);
                        if ((k0 + mt * 16 + quad * 4 + r) > qg) arg = -1e30f;
                        pk[r] = (bf16)exp2f(arg);
                    }
                } else {
                    #pragma unroll
                    for (int r = 0; r < 4; ++r)
                        pk[r] = (bf16)exp2f(fmaf(st[r], C_SL, -16.f));
                }
                *(bf16x4*)&Pw[(nt * 16 + col) * QS + mt * 16 + quad * 4] = pk;
            }
        }
        // P readback (wave-private, no barrier) + O += P V, l += P 1
        #pragma unroll
        for (int mg = 0; mg < 2; ++mg) {
            bf16x8 ap0 = *(const bf16x8*)&Pw[(mg * 16 + col) * QS + quad * 8];
            bf16x8 ap1 = *(const bf16x8*)&Pw[(mg * 16 + col) * QS + 32 + quad * 8];
            #pragma unroll
            for (int nd = 0; nd < 4; ++nd) {
                bf16x8 bv0 = *(const bf16x8*)&Vt[vsw(nd * 16 + col, quad * 8)];
                bf16x8 bv1 = *(const bf16x8*)&Vt[vsw(nd * 16 + col, 32 + quad * 8)];
                of[mg][nd] = __builtin_amdgcn_mfma_f32_16x16x32_bf16(ap0, bv0, of[mg][nd], 0, 0, 0);
                of[mg][nd] = __builtin_amdgcn_mfma_f32_16x16x32_bf16(ap1, bv1, of[mg][nd], 0, 0, 0);
            }
            lac[mg] = __builtin_amdgcn_mfma_f32_16x16x32_bf16(ap0, bones, lac[mg], 0, 0, 0);
            lac[mg] = __builtin_amdgcn_mfma_f32_16x16x32_bf16(ap1, bones, lac[mg], 0, 0, 0);
        }
    }
    // epilogue: y into this block's dead Q region; l is in O's C-layout
    #pragma unroll
    for (int mg = 0; mg < 2; ++mg)
        #pragma unroll
        for (int r = 0; r < 4; ++r) {
            float inv = 1.f / lac[mg][r];
            long yoff = base + (long)(q0 + wid * 32 + mg * 16 + quad * 4 + r) * D3;
            #pragma unroll
            for (int nd = 0; nd < 4; ++nd)
                qkv[yoff + nd * 16 + col] = (bf16)(of[mg][nd][r] * inv);
        }
}

// --------------------------------------------------------------------------
extern "C" void kernel_launch(void* const* d_in, const int* in_sizes, int n_in,
                              void* d_out, int out_size, void* d_ws, size_t ws_size,
                              hipStream_t stream) {
    const float* x      = (const float*)d_in[0];  // [8192,1024] fp32
    const float* W_attn = (const float*)d_in[1];  // [1024,3072] fp32
    const float* W_proj = (const float*)d_in[2];  // [1024,1024] fp32
    float* out = (float*)d_out;                   // [8192,1024] fp32

    // ws layout (58.7 MB): qkv | WtA | WtP
    bf16* qkv = (bf16*)d_ws;                         // [8192,3072]  50.3 MB
    bf16* WtA = qkv + (size_t)8192 * 3072;           // [3072,1024]   6.3 MB
    bf16* WtP = WtA + (size_t)3072 * 1024;           // [1024,1024]   2.1 MB
    bf16* xb = (bf16*)d_out;   // bf16 x staged in d_out; dead before gemm2

    cast_f32_bf16<<<8192, 256, 0, stream>>>(x, xb, 8192 * 1024 / 4);
    transpose_f32_bf16<<<dim3(48, 16), 256, 0, stream>>>(W_attn, WtA, 1024, 3072);
    transpose_f32_bf16<<<dim3(16, 16), 256, 0, stream>>>(W_proj, WtP, 1024, 1024);
    // qkv = xb @ W_attn  (bf16 out)
    gemm_bt<bf16><<<dim3(24, 64), 256, 0, stream>>>(xb, WtA, qkv, 8192, 3072,
                                                    1024, 1024, 3072);
    // MFMA flash attention; y written into qkv's Q columns
    attn_mfma<<<1024, 256, 0, stream>>>(qkv);
    // out = y @ W_proj  (y = qkv cols 0..1023, row stride 3072; fp32 out)
    gemm_bt<float><<<dim3(8, 64), 256, 0, stream>>>(qkv, WtP, out, 8192, 1024,
                                                    1024, 3072, 1024);
}